// Round 1
// baseline (224.678 us; speedup 1.0000x reference)
//
#include <hip/hip_runtime.h>
#include <hip/hip_bf16.h>
#include <cstdint>
#include <cstddef>

// Problem dims (fixed by the reference).
#define M_DIM 8192
#define K_DIM 2048
#define N_DIM 2048

// GEMM tile config (m97-class structure from the CDNA4 guide).
#define BM 128
#define BN 128
#define BK 32

typedef __bf16 bf16x8 __attribute__((ext_vector_type(8)));
typedef float f32x4 __attribute__((ext_vector_type(4)));
typedef unsigned short ushort8_t __attribute__((ext_vector_type(8)));

__device__ __forceinline__ unsigned short f32_to_bf16_rne(float f) {
  unsigned int u = __builtin_bit_cast(unsigned int, f);
  u += 0x7fffu + ((u >> 16) & 1u);
  return (unsigned short)(u >> 16);
}

// ---------------------------------------------------------------------------
// Kernel 1: convert x (f32 [M,K]) -> bf16 [M,K], vectorized 8 elems/thread.
// ---------------------------------------------------------------------------
__global__ void cvt_x_kernel(const float* __restrict__ x,
                             unsigned short* __restrict__ xb) {
  const size_t n = (size_t)M_DIM * K_DIM;
  size_t i = ((size_t)blockIdx.x * blockDim.x + threadIdx.x) * 8;
  const size_t stride = (size_t)gridDim.x * blockDim.x * 8;
  for (; i < n; i += stride) {
    const float4 f0 = *reinterpret_cast<const float4*>(x + i);
    const float4 f1 = *reinterpret_cast<const float4*>(x + i + 4);
    ushort8_t o;
    o[0] = f32_to_bf16_rne(f0.x);
    o[1] = f32_to_bf16_rne(f0.y);
    o[2] = f32_to_bf16_rne(f0.z);
    o[3] = f32_to_bf16_rne(f0.w);
    o[4] = f32_to_bf16_rne(f1.x);
    o[5] = f32_to_bf16_rne(f1.y);
    o[6] = f32_to_bf16_rne(f1.z);
    o[7] = f32_to_bf16_rne(f1.w);
    *reinterpret_cast<ushort8_t*>(xb + i) = o;
  }
}

// ---------------------------------------------------------------------------
// Kernel 2: w (f32 [K,N]) -> wt (bf16 [N,K]) transpose via LDS 64x64 tiles.
// Both global sides coalesced; LDS pad 65 makes read tile[tx][row] conflict-free.
// ---------------------------------------------------------------------------
__global__ void cvt_wt_kernel(const float* __restrict__ w,
                              unsigned short* __restrict__ wt) {
  __shared__ float tile[64][65];
  const int tx = threadIdx.x & 63;
  const int ty = threadIdx.x >> 6;  // 0..3
  const int n0 = blockIdx.x * 64;
  const int k0 = blockIdx.y * 64;
#pragma unroll
  for (int r = 0; r < 16; ++r) {
    const int row = r * 4 + ty;  // k-local
    tile[row][tx] = w[(size_t)(k0 + row) * N_DIM + n0 + tx];
  }
  __syncthreads();
#pragma unroll
  for (int r = 0; r < 16; ++r) {
    const int row = r * 4 + ty;  // n-local
    wt[(size_t)(n0 + row) * K_DIM + k0 + tx] = f32_to_bf16_rne(tile[tx][row]);
  }
}

// ---------------------------------------------------------------------------
// Kernel 3: bf16 GEMM, C[M,N] f32 = A[M,K] * Bt[N,K]^T.
// 128x128 tile, BK=32, 4 waves (2x2), each wave 64x64 = 4x4 fragments of
// 16x16x32 MFMA. global_load_lds width-16 staging into linear LDS.
// ---------------------------------------------------------------------------
__device__ __forceinline__ void async_copy16(unsigned short* lds_dst,
                                             const unsigned short* g_src) {
  __builtin_amdgcn_global_load_lds(
      (__attribute__((address_space(1))) void*)g_src,
      (__attribute__((address_space(3))) void*)lds_dst,
      16, 0, 0);
}

__global__ __launch_bounds__(256) void gemm_kernel(
    const unsigned short* __restrict__ A,   // bf16 [M,K]
    const unsigned short* __restrict__ Bt,  // bf16 [N,K]
    float* __restrict__ C) {                // f32 [M,N]
  __shared__ unsigned short sA[BM * BK];  // 8 KiB, linear row-major [128][32]
  __shared__ unsigned short sB[BN * BK];  // 8 KiB

  const int tid = threadIdx.x;
  const int lane = tid & 63;
  const int wv = tid >> 6;  // 0..3

  // XCD-aware bijective swizzle: nwg = 1024, 8 XCDs, 128 blocks per XCD chunk.
  const int bid = blockIdx.x;
  const int wgid = (bid & 7) * 128 + (bid >> 3);
  const int bm = wgid >> 4;   // 0..63  (N/BN = 16 tiles per row)
  const int bn = wgid & 15;   // 0..15
  const int m0 = bm * BM;
  const int n0 = bn * BN;

  const int wm = wv >> 1;     // 0..1
  const int wn = wv & 1;      // 0..1
  const int lr = lane & 15;   // fragment row/col
  const int kg = lane >> 4;   // k-group 0..3

  f32x4 acc[4][4] = {};

  for (int k0 = 0; k0 < K_DIM; k0 += BK) {
    // --- stage A and B tiles (each 8192 B = 512 chunks of 16 B) ---
#pragma unroll
    for (int j = 0; j < 2; ++j) {
      const int chunk = j * 256 + wv * 64 + lane;  // 0..511
      const int row = chunk >> 2;                  // 0..127 (4 chunks per 64B row)
      const int kp = chunk & 3;
      const int lds_base = (j * 256 + wv * 64) * 8;  // wave-uniform, in ushort elems
      async_copy16(&sA[lds_base],
                   A + (size_t)(m0 + row) * K_DIM + k0 + kp * 8);
      async_copy16(&sB[lds_base],
                   Bt + (size_t)(n0 + row) * K_DIM + k0 + kp * 8);
    }
    __syncthreads();  // compiler drains vmcnt(0) before barrier

    // --- fragment loads (ds_read_b128) + 16 MFMA ---
    bf16x8 af[4], bfr[4];
#pragma unroll
    for (int mi = 0; mi < 4; ++mi)
      af[mi] = *reinterpret_cast<const bf16x8*>(
          &sA[(wm * 64 + mi * 16 + lr) * BK + kg * 8]);
#pragma unroll
    for (int ni = 0; ni < 4; ++ni)
      bfr[ni] = *reinterpret_cast<const bf16x8*>(
          &sB[(wn * 64 + ni * 16 + lr) * BK + kg * 8]);
#pragma unroll
    for (int mi = 0; mi < 4; ++mi)
#pragma unroll
      for (int ni = 0; ni < 4; ++ni)
        acc[mi][ni] = __builtin_amdgcn_mfma_f32_16x16x32_bf16(
            af[mi], bfr[ni], acc[mi][ni], 0, 0, 0);
    __syncthreads();  // protect LDS before next-tile overwrite
  }

  // --- epilogue: C/D layout col = lane&15, row = (lane>>4)*4 + reg ---
#pragma unroll
  for (int mi = 0; mi < 4; ++mi) {
#pragma unroll
    for (int ni = 0; ni < 4; ++ni) {
#pragma unroll
      for (int r = 0; r < 4; ++r) {
        C[(size_t)(m0 + wm * 64 + mi * 16 + kg * 4 + r) * N_DIM +
          (n0 + wn * 64 + ni * 16 + lr)] = acc[mi][ni][r];
      }
    }
  }
}

// ---------------------------------------------------------------------------
extern "C" void kernel_launch(void* const* d_in, const int* in_sizes, int n_in,
                              void* d_out, int out_size, void* d_ws,
                              size_t ws_size, hipStream_t stream) {
  const float* x = (const float*)d_in[0];  // [M,K] f32
  const float* w = (const float*)d_in[1];  // [K,N] f32
  float* out = (float*)d_out;              // [M,N] f32

  unsigned short* xb = (unsigned short*)d_ws;                       // 32 MiB
  unsigned short* wt = (unsigned short*)((char*)d_ws +
                                         (size_t)M_DIM * K_DIM * 2);  // 8 MiB

  cvt_x_kernel<<<2048, 256, 0, stream>>>(x, xb);
  cvt_wt_kernel<<<dim3(N_DIM / 64, K_DIM / 64), 256, 0, stream>>>(w, wt);

  const int grid = (M_DIM / BM) * (N_DIM / BN);  // 64*16 = 1024
  gemm_kernel<<<grid, 256, 0, stream>>>(xb, wt, out);
}

// Round 2
// 182.891 us; speedup vs baseline: 1.2285x; 1.2285x over previous
//
#include <hip/hip_runtime.h>
#include <hip/hip_bf16.h>
#include <cstdint>
#include <cstddef>

// Problem dims (fixed by the reference).
#define M_DIM 8192
#define K_DIM 2048
#define N_DIM 2048

// 256x256 8-phase template (HK-derived, guide §5).
#define BM 256
#define BN 256
#define BK 64
#define NITER (K_DIM / BK / 2)  // 16 iterations, 2 K-tiles each

typedef __bf16 bf16x8 __attribute__((ext_vector_type(8)));
typedef float f32x4 __attribute__((ext_vector_type(4)));
typedef unsigned short ushort8_t __attribute__((ext_vector_type(8)));

__device__ __forceinline__ unsigned short f32_to_bf16_rne(float f) {
  unsigned int u = __builtin_bit_cast(unsigned int, f);
  u += 0x7fffu + ((u >> 16) & 1u);
  return (unsigned short)(u >> 16);
}

// ---------------------------------------------------------------------------
// Kernel 1: x (f32 [M,K]) -> bf16 [M,K].
// ---------------------------------------------------------------------------
__global__ void cvt_x_kernel(const float* __restrict__ x,
                             unsigned short* __restrict__ xb) {
  const size_t n = (size_t)M_DIM * K_DIM;
  size_t i = ((size_t)blockIdx.x * blockDim.x + threadIdx.x) * 8;
  const size_t stride = (size_t)gridDim.x * blockDim.x * 8;
  for (; i < n; i += stride) {
    const float4 f0 = *reinterpret_cast<const float4*>(x + i);
    const float4 f1 = *reinterpret_cast<const float4*>(x + i + 4);
    ushort8_t o;
    o[0] = f32_to_bf16_rne(f0.x);
    o[1] = f32_to_bf16_rne(f0.y);
    o[2] = f32_to_bf16_rne(f0.z);
    o[3] = f32_to_bf16_rne(f0.w);
    o[4] = f32_to_bf16_rne(f1.x);
    o[5] = f32_to_bf16_rne(f1.y);
    o[6] = f32_to_bf16_rne(f1.z);
    o[7] = f32_to_bf16_rne(f1.w);
    *reinterpret_cast<ushort8_t*>(xb + i) = o;
  }
}

// ---------------------------------------------------------------------------
// Kernel 2: w (f32 [K,N]) -> wt (bf16 [N,K]) transpose via LDS 64x64 tiles.
// ---------------------------------------------------------------------------
__global__ void cvt_wt_kernel(const float* __restrict__ w,
                              unsigned short* __restrict__ wt) {
  __shared__ float tile[64][65];
  const int tx = threadIdx.x & 63;
  const int ty = threadIdx.x >> 6;  // 0..3
  const int n0 = blockIdx.x * 64;
  const int k0 = blockIdx.y * 64;
#pragma unroll
  for (int r = 0; r < 16; ++r) {
    const int row = r * 4 + ty;  // k-local
    tile[row][tx] = w[(size_t)(k0 + row) * N_DIM + n0 + tx];
  }
  __syncthreads();
#pragma unroll
  for (int r = 0; r < 16; ++r) {
    const int row = r * 4 + ty;  // n-local
    wt[(size_t)(n0 + row) * K_DIM + k0 + tx] = f32_to_bf16_rne(tile[tx][row]);
  }
}

// ---------------------------------------------------------------------------
// Kernel 3: 256x256 8-phase bf16 GEMM. C[M,N] f32 = A[M,K] * Bt[N,K]^T.
// 8 waves (2M x 4N), per-wave 128x64 output. LDS 128 KiB double-buffered.
// Both-sides XOR swizzle: LDS slot s of row r holds global k-slot s^(r&7);
// staged linearly by global_load_lds from inverse-swizzled global addresses.
// ---------------------------------------------------------------------------
__device__ __forceinline__ void async_copy16(unsigned short* lds_dst,
                                             const unsigned short* g_src) {
  __builtin_amdgcn_global_load_lds(
      (__attribute__((address_space(1))) void*)g_src,
      (__attribute__((address_space(3))) void*)lds_dst,
      16, 0, 0);
}

#define BARR() __builtin_amdgcn_s_barrier()
#define LGKM0()                                       \
  asm volatile("s_waitcnt lgkmcnt(0)" ::: "memory");  \
  __builtin_amdgcn_sched_barrier(0)
#define PRIO(p) __builtin_amdgcn_s_setprio(p)

// Stage one half-tile (128 rows x 64 k) of A (isB=0) or B (isB=1), half h,
// K-tile t, into buf (t&1). 2 x global_load_lds(16B) per thread.
#define STG(isB, h, t)                                                       \
  do {                                                                       \
    const unsigned short* _src =                                             \
        ((isB) ? Bt : A) +                                                   \
        (size_t)(((isB) ? n0 : m0) + (h) * 128 + row0) * K_DIM + (t) * 64 +  \
        sg8;                                                                 \
    unsigned short* _dst = &smem[((t) & 1) * 32768 + (isB) * 16384 +         \
                                 (h) * 8192 + dst0];                         \
    async_copy16(_dst, _src);                                                \
    async_copy16(_dst + 4096, _src + 64 * K_DIM);                            \
  } while (0)

// ds_read the wave's A fragments for M-half moff (4 frags x 2 kslices).
#define RD_A(buf, moff)                                                      \
  do {                                                                       \
    _Pragma("unroll") for (int mf = 0; mf < 4; ++mf) {                       \
      const int _r = ((buf) * 32768) + (wm * 128 + ((moff) + mf) * 16 + lr) * 64; \
      a[mf][0] = *reinterpret_cast<const bf16x8*>(&smem[_r + sl0]);          \
      a[mf][1] = *reinterpret_cast<const bf16x8*>(&smem[_r + sl1]);          \
    }                                                                        \
  } while (0)

// ds_read the wave's B fragments for N-half noff into bdst (2 frags x 2 ks).
#define RD_B(bdst, buf, noff)                                                \
  do {                                                                       \
    _Pragma("unroll") for (int nf = 0; nf < 2; ++nf) {                       \
      const int _r = ((buf) * 32768) + 16384 +                               \
                     (wn * 64 + ((noff) + nf) * 16 + lr) * 64;               \
      bdst[nf][0] = *reinterpret_cast<const bf16x8*>(&smem[_r + sl0]);       \
      bdst[nf][1] = *reinterpret_cast<const bf16x8*>(&smem[_r + sl1]);       \
    }                                                                        \
  } while (0)

// 16 MFMA: one C-quadrant (4 m-frags x 2 n-frags x 2 kslices).
#define MM(bsel, moff, noff)                                                 \
  do {                                                                       \
    _Pragma("unroll") for (int mf = 0; mf < 4; ++mf) {                       \
      _Pragma("unroll") for (int nf = 0; nf < 2; ++nf) {                     \
        _Pragma("unroll") for (int ks = 0; ks < 2; ++ks) {                   \
          acc[(moff) + mf][(noff) + nf] =                                    \
              __builtin_amdgcn_mfma_f32_16x16x32_bf16(                       \
                  a[mf][ks], bsel[nf][ks], acc[(moff) + mf][(noff) + nf],    \
                  0, 0, 0);                                                  \
        }                                                                    \
      }                                                                      \
    }                                                                        \
  } while (0)

__global__ __launch_bounds__(512, 2) void gemm_kernel(
    const unsigned short* __restrict__ A,   // bf16 [M,K]
    const unsigned short* __restrict__ Bt,  // bf16 [N,K]
    float* __restrict__ C) {                // f32 [M,N]
  __shared__ unsigned short smem[2 * 32768];  // 128 KiB: [buf][A|B][256][64]

  const int tid = threadIdx.x;
  const int lane = tid & 63;
  const int wv = tid >> 6;          // 0..7
  const int wm = wv >> 2;           // 0..1
  const int wn = wv & 3;            // 0..3
  const int lr = lane & 15;
  const int kg = lane >> 4;         // 0..3
  // Swizzled ds_read slot offsets (elements): slot = (ks*4+kg) ^ (row&7),
  // and row&7 == lr&7 for all fragment rows.
  const int sl0 = ((kg ^ (lr & 7)) * 8);
  const int sl1 = (((kg + 4) ^ (lr & 7)) * 8);

  // XCD-aware chunked swizzle (nwg=256, divisible by 8).
  const int bid = blockIdx.x;
  const int wgid = (bid & 7) * 32 + (bid >> 3);
  const int bm = wgid >> 3;  // 0..31
  const int bn = wgid & 7;   // 0..7
  const int m0 = bm * BM;
  const int n0 = bn * BN;

  // Staging constants: thread covers chunks c = l*512 + tid (l=0,1);
  // row = c>>3, lds slot = c&7, global slot = (c&7) ^ (row&7).
  const int row0 = tid >> 3;                                  // 0..63
  const int sg8 = (((tid & 7) ^ ((tid >> 3) & 7)) * 8);       // global k-offset
  const int dst0 = wv * 512;  // wave-uniform LDS elem offset within region

  f32x4 acc[8][4] = {};
  bf16x8 a[4][2], b0[2][2], b1[2][2];

  // Prologue: tile0 fully (A0,A1,B0,B1) + tile1 B halves. A halves of tile1
  // are staged in P1/P2 of iteration 0.
  STG(0, 0, 0); STG(0, 1, 0); STG(1, 0, 0); STG(1, 1, 0);
  STG(1, 0, 1); STG(1, 1, 1);
  asm volatile("s_waitcnt vmcnt(4)" ::: "memory");  // tile0 arrived
  BARR();

#pragma unroll 1
  for (int j = 0; j < NITER; ++j) {
    const int e = 2 * j;      // even K-tile -> buf0
    const int o = 2 * j + 1;  // odd K-tile  -> buf1
    const bool more = (j + 1 < NITER);

    // ---- P1: Q00 of tile e ----
    RD_A(0, 0); RD_B(b0, 0, 0);
    STG(0, 0, o);  // A-half0 of odd tile (buf1-A freed end of prev P7)
    asm volatile("s_waitcnt lgkmcnt(8)" ::: "memory");
    BARR(); LGKM0(); PRIO(1); MM(b0, 0, 0); PRIO(0); BARR();
    // ---- P2: Q01 ----
    RD_B(b1, 0, 2);
    STG(0, 1, o);  // A-half1 of odd tile
    BARR(); LGKM0(); PRIO(1); MM(b1, 0, 2); PRIO(0); BARR();
    // ---- P3: Q10 ----
    RD_A(0, 4);
    if (more) STG(1, 0, e + 2);  // B-half0 of tile e+2 (buf0-B freed end P2)
    BARR(); LGKM0(); PRIO(1); MM(b0, 4, 0); PRIO(0); BARR();
    // ---- P4: Q11 (no new ds_reads) ----
    if (more) {
      STG(1, 1, e + 2);  // B-half1 of tile e+2
      asm volatile("s_waitcnt vmcnt(4)" ::: "memory");  // odd tile ready
    } else {
      asm volatile("s_waitcnt vmcnt(0)" ::: "memory");
    }
    BARR(); PRIO(1); MM(b1, 4, 2); PRIO(0); BARR();

    // ---- P5: Q00 of tile o ----
    RD_A(1, 0); RD_B(b0, 1, 0);
    if (more) STG(0, 0, e + 2);  // A-half0 of tile e+2 (buf0-A freed end P3)
    asm volatile("s_waitcnt lgkmcnt(8)" ::: "memory");
    BARR(); LGKM0(); PRIO(1); MM(b0, 0, 0); PRIO(0); BARR();
    // ---- P6: Q01 ----
    RD_B(b1, 1, 2);
    if (more) STG(0, 1, e + 2);  // A-half1 of tile e+2
    BARR(); LGKM0(); PRIO(1); MM(b1, 0, 2); PRIO(0); BARR();
    // ---- P7: Q10 ----
    RD_A(1, 4);
    if (more) STG(1, 0, o + 2);  // B-half0 of tile o+2 (buf1-B freed end P6)
    BARR(); LGKM0(); PRIO(1); MM(b0, 4, 0); PRIO(0); BARR();
    // ---- P8: Q11 ----
    if (more) {
      STG(1, 1, o + 2);  // B-half1 of tile o+2
      asm volatile("s_waitcnt vmcnt(4)" ::: "memory");  // tile e+2 ready
    }
    BARR(); PRIO(1); MM(b1, 4, 2); PRIO(0); BARR();
  }

  // Epilogue: C/D layout col = lane&15, row = kg*4 + reg.
  const int crow0 = m0 + wm * 128 + kg * 4;
  const int ccol0 = n0 + wn * 64 + lr;
#pragma unroll
  for (int mi = 0; mi < 8; ++mi) {
#pragma unroll
    for (int ni = 0; ni < 4; ++ni) {
#pragma unroll
      for (int r = 0; r < 4; ++r) {
        C[(size_t)(crow0 + mi * 16 + r) * N_DIM + ccol0 + ni * 16] =
            acc[mi][ni][r];
      }
    }
  }
}

// ---------------------------------------------------------------------------
extern "C" void kernel_launch(void* const* d_in, const int* in_sizes, int n_in,
                              void* d_out, int out_size, void* d_ws,
                              size_t ws_size, hipStream_t stream) {
  const float* x = (const float*)d_in[0];  // [M,K] f32
  const float* w = (const float*)d_in[1];  // [K,N] f32
  float* out = (float*)d_out;              // [M,N] f32

  unsigned short* xb = (unsigned short*)d_ws;                         // 32 MiB
  unsigned short* wt = (unsigned short*)((char*)d_ws +
                                         (size_t)M_DIM * K_DIM * 2);  // 8 MiB

  cvt_x_kernel<<<2048, 256, 0, stream>>>(x, xb);
  cvt_wt_kernel<<<dim3(N_DIM / 64, K_DIM / 64), 256, 0, stream>>>(w, wt);

  const int grid = (M_DIM / BM) * (N_DIM / BN);  // 32 * 8 = 256
  gemm_kernel<<<grid, 512, 0, stream>>>(xb, wt, out);
}